// Round 20
// baseline (817.840 us; speedup 1.0000x reference)
//
#include <hip/hip_runtime.h>

using u16 = unsigned short;
typedef __bf16 bf16x8 __attribute__((ext_vector_type(8)));
typedef float f32x4 __attribute__((ext_vector_type(4)));

__device__ inline u16 f2bf(float f){
  unsigned u = __float_as_uint(f);
  u += 0x7fff + ((u >> 16) & 1);   // RNE
  return (u16)(u >> 16);
}
__device__ inline float bf2f(u16 u){ return __uint_as_float((unsigned)u << 16); }

__device__ inline float wredsum(float v){
  #pragma unroll
  for (int o = 32; o; o >>= 1) v += __shfl_xor(v, o, 64);
  return v;
}

// direct global -> LDS DMA, 16B per lane; lds base must be wave-uniform
__device__ inline void gld16(const u16* g, u16* lds){
  __builtin_amdgcn_global_load_lds(
      (const __attribute__((address_space(1))) unsigned int*)g,
      (__attribute__((address_space(3))) unsigned int*)lds, 16, 0, 0);
}

// ---------------- mod matvec, K-split x4 (R19) ----------------
__global__ void mod_mv_k(const float* __restrict__ vec,
    const float* __restrict__ wi, const float* __restrict__ wt,
    float* __restrict__ part)
{
  __shared__ float sv[512];
  __shared__ float red[4][64];
  int tid = threadIdx.x;
  int z = blockIdx.y;
  int k0 = z * 512;
  for (int i = tid; i < 512; i += 256){ float v = vec[k0 + i]; sv[i] = v / (1.0f + __expf(-v)); }
  __syncthreads();
  int j0 = blockIdx.x * 64;
  bool ist = j0 >= 12288;
  const float* w = ist ? wt : wi;
  int col = (ist ? j0 - 12288 : j0) + (tid & 63);
  int kq = tid >> 6;
  float acc = 0.f;
  const float* wp = w + (long long)k0 * 12288 + col;
  for (int k = kq * 128; k < kq * 128 + 128; ++k) acc += sv[k] * wp[(long long)k * 12288];
  red[kq][tid & 63] = acc;
  __syncthreads();
  if (kq == 0)
    part[(long long)z * 24576 + j0 + tid] = red[0][tid] + red[1][tid] + red[2][tid] + red[3][tid];
}

__global__ void mod_comb_k(const float* __restrict__ part,
    const float* __restrict__ bi, const float* __restrict__ bt,
    float* __restrict__ oi, float* __restrict__ ot)
{
  int idx = blockIdx.x * 256 + threadIdx.x;   // 0..24575
  float s = part[idx] + part[24576 + idx] + part[2 * 24576 + idx] + part[3 * 24576 + idx];
  if (idx >= 12288) ot[idx - 12288] = s + bt[idx - 12288];
  else              oi[idx] = s + bi[idx];
}

// ---------------- merged transpose + cast, 64x64 tiles ----------------
struct TcArgs {
  const float* in[8];
  u16* out[8];
  int K[8];
  int N[8];
  int base[9];
};

__global__ void tcast64_k(TcArgs a)
{
  __shared__ float tile[64][65];
  int bid = blockIdx.x;
  int w = 0;
  #pragma unroll
  for (int i = 0; i < 8; ++i) if (bid >= a.base[i + 1]) w = i + 1;
  const float* in = a.in[w];
  u16* out = a.out[w];
  int K = a.K[w], N = a.N[w];
  int local = bid - a.base[w];
  int tx = N >> 6;
  int n0 = (local % tx) * 64, k0 = (local / tx) * 64;
  int tid = threadIdx.x;
  int r = tid >> 2, c0 = (tid & 3) * 16;
  const float* ir = &in[(long long)(k0 + r) * N + n0 + c0];
  #pragma unroll
  for (int j = 0; j < 4; ++j){
    float4 v = *(const float4*)&ir[j * 4];
    tile[r][c0 + j * 4 + 0] = v.x; tile[r][c0 + j * 4 + 1] = v.y;
    tile[r][c0 + j * 4 + 2] = v.z; tile[r][c0 + j * 4 + 3] = v.w;
  }
  __syncthreads();
  int n = tid >> 2, ks = (tid & 3) * 16;
  u16* orow = &out[(long long)(n0 + n) * K + k0 + ks];
  #pragma unroll
  for (int j = 0; j < 4; ++j){
    ushort4 o;
    o.x = f2bf(tile[ks + j * 4 + 0][n]);
    o.y = f2bf(tile[ks + j * 4 + 1][n]);
    o.z = f2bf(tile[ks + j * 4 + 2][n]);
    o.w = f2bf(tile[ks + j * 4 + 3][n]);
    *(ushort4*)&orow[j * 4] = o;
  }
}

// ---------------- LayerNorm + modulate (img+txt merged) ----------------
__global__ void ln_mod_k(const float* __restrict__ xi, const float* __restrict__ xt,
    const float* __restrict__ sh_i, const float* __restrict__ sc_i,
    const float* __restrict__ sh_t, const float* __restrict__ sc_t,
    u16* __restrict__ oi, u16* __restrict__ ot)
{
  int row = blockIdx.x, tid = threadIdx.x;
  bool ist = row >= 2048;
  int r = ist ? row - 2048 : row;
  const float* xr = (ist ? xt : xi) + (long long)r * 2048;
  const float* sh = ist ? sh_t : sh_i;
  const float* sc = ist ? sc_t : sc_i;
  u16* orow = (ist ? ot : oi) + (long long)r * 2048;
  float v[8]; float s = 0.f, s2 = 0.f;
  #pragma unroll
  for (int j = 0; j < 8; ++j){ v[j] = xr[tid + j * 256]; s += v[j]; s2 += v[j] * v[j]; }
  s = wredsum(s); s2 = wredsum(s2);
  __shared__ float red[4][2];
  int wave = tid >> 6, lane = tid & 63;
  if (lane == 0){ red[wave][0] = s; red[wave][1] = s2; }
  __syncthreads();
  float S1 = red[0][0] + red[1][0] + red[2][0] + red[3][0];
  float S2 = red[0][1] + red[1][1] + red[2][1] + red[3][1];
  float mu = S1 * (1.0f / 2048.0f);
  float var = S2 * (1.0f / 2048.0f) - mu * mu;
  float rs = rsqrtf(var + 1e-6f);
  #pragma unroll
  for (int j = 0; j < 8; ++j){
    int c = tid + j * 256;
    orow[c] = f2bf((1.0f + sc[c]) * (v[j] - mu) * rs + sh[c]);
  }
}

// ======== fused flash attention, KV=64 tiles, 80KB LDS (R16) ========
__global__ __launch_bounds__(512)
void fattn_k(const u16* __restrict__ Qb, const u16* __restrict__ Kb,
             const u16* __restrict__ Vt, u16* __restrict__ attn)
{
  __shared__ u16 Kl[2][64 * 128];
  __shared__ u16 Vl[2][128 * 64];
  __shared__ u16 Pl[128 * 64];

  const int tid  = threadIdx.x;
  const int lane = tid & 63;
  const int wave = tid >> 6;
  const int h  = blockIdx.y;
  const int q0 = blockIdx.x * 128;

  const u16* Qg = Qb + ((long long)h * 2304 + q0) * 128;
  const u16* Kg = Kb + (long long)h * 2304 * 128;
  const u16* Vg = Vt + (long long)h * 128 * 2304;

  u16* Qlds = &Kl[0][0];

  const int r16 = wave * 4 + (lane >> 4);
  const int o16 = lane & 15;
  const int r8 = wave * 8 + (lane >> 3);
  const int o8 = lane & 7;

  #pragma unroll
  for (int i = 0; i < 4; ++i){
    int row = i * 32 + r16;
    gld16(Qg + (long long)row * 128 + ((o16 ^ (row & 7)) * 8),
          Qlds + (i * 32 + wave * 4) * 128);
  }
  __syncthreads();

  const int frow = lane & 15;
  const int j0   = lane >> 4;
  const int qrow = wave * 16 + frow;
  bf16x8 aq[4];
  #pragma unroll
  for (int s = 0; s < 4; ++s)
    aq[s] = *(const bf16x8*)&Qlds[qrow * 128 + (((s * 4 + j0) ^ (qrow & 7)) * 8)];
  __syncthreads();

  auto stageK = [&](int t, int b){
    #pragma unroll
    for (int i = 0; i < 2; ++i){
      int row = i * 32 + r16;
      gld16(Kg + (long long)(t * 64 + row) * 128 + ((o16 ^ (row & 7)) * 8),
            &Kl[b][(i * 32 + wave * 4) * 128]);
    }
  };
  auto stageV = [&](int t, int b){
    #pragma unroll
    for (int i = 0; i < 2; ++i){
      int row = i * 64 + r8;
      gld16(Vg + (long long)row * 2304 + t * 64 + ((o8 ^ (row & 7)) * 8),
            &Vl[b][(i * 64 + wave * 8) * 64]);
    }
  };

  stageK(0, 0); stageV(0, 0);
  __builtin_amdgcn_sched_barrier(0);

  float mrun[4], lrun[4];
  #pragma unroll
  for (int j = 0; j < 4; ++j){ mrun[j] = -3.0e38f; lrun[j] = 0.f; }
  f32x4 oacc[8] = {};

  for (int t = 0; t < 36; ++t){
    const int cur = t & 1;
    asm volatile("s_waitcnt vmcnt(0)" ::: "memory");
    __builtin_amdgcn_sched_barrier(0);
    __builtin_amdgcn_s_barrier();
    __builtin_amdgcn_sched_barrier(0);
    if (t + 1 < 36){ stageK(t + 1, cur ^ 1); stageV(t + 1, cur ^ 1); }
    __builtin_amdgcn_sched_barrier(0);

    f32x4 sacc[4] = {};
    #pragma unroll
    for (int s = 0; s < 4; ++s){
      #pragma unroll
      for (int n = 0; n < 4; ++n){
        int kr = n * 16 + frow;
        bf16x8 bk = *(const bf16x8*)&Kl[cur][kr * 128 + (((s * 4 + j0) ^ (kr & 7)) * 8)];
        sacc[n] = __builtin_amdgcn_mfma_f32_16x16x32_bf16(aq[s], bk, sacc[n], 0, 0, 0);
      }
    }

    float mnew[4], scl[4];
    #pragma unroll
    for (int j = 0; j < 4; ++j){
      float v = fmaxf(fmaxf(sacc[0][j], sacc[1][j]), fmaxf(sacc[2][j], sacc[3][j]));
      #pragma unroll
      for (int o = 8; o; o >>= 1) v = fmaxf(v, __shfl_xor(v, o, 64));
      mnew[j] = fmaxf(mrun[j], v);
      scl[j] = __expf(mrun[j] - mnew[j]);
      mrun[j] = mnew[j];
    }
    #pragma unroll
    for (int j = 0; j < 4; ++j){
      const int row = wave * 16 + j0 * 4 + j;
      float rsum = 0.f;
      #pragma unroll
      for (int n = 0; n < 4; ++n){
        float p = __expf(sacc[n][j] - mnew[j]);
        rsum += p;
        int col = n * 16 + frow;
        Pl[row * 64 + (((col >> 3) ^ (row & 7)) << 3) + (col & 7)] = f2bf(p);
      }
      #pragma unroll
      for (int o = 8; o; o >>= 1) rsum += __shfl_xor(rsum, o, 64);
      lrun[j] = lrun[j] * scl[j] + rsum;
      #pragma unroll
      for (int n = 0; n < 8; ++n) oacc[n][j] *= scl[j];
    }
    asm volatile("s_waitcnt lgkmcnt(0)" ::: "memory");
    __builtin_amdgcn_sched_barrier(0);

    #pragma unroll
    for (int s = 0; s < 2; ++s){
      bf16x8 ap = *(const bf16x8*)&Pl[qrow * 64 + (((s * 4 + j0) ^ (qrow & 7)) * 8)];
      #pragma unroll
      for (int n = 0; n < 8; ++n){
        int dr = n * 16 + frow;
        bf16x8 bv = *(const bf16x8*)&Vl[cur][dr * 64 + (((s * 4 + j0) ^ (dr & 7)) * 8)];
        oacc[n] = __builtin_amdgcn_mfma_f32_16x16x32_bf16(ap, bv, oacc[n], 0, 0, 0);
      }
    }
    __builtin_amdgcn_sched_barrier(0);
  }

  float inv[4];
  #pragma unroll
  for (int j = 0; j < 4; ++j) inv[j] = 1.0f / lrun[j];
  #pragma unroll
  for (int n = 0; n < 8; ++n){
    int d = n * 16 + frow;
    #pragma unroll
    for (int j = 0; j < 4; ++j){
      int row = wave * 16 + j0 * 4 + j;
      attn[(long long)(q0 + row) * 2048 + h * 128 + d] = f2bf(oacc[n][j] * inv[j]);
    }
  }
}

// ======== gemm10: 8-phase interleaved GEMM, 256x256, BK=64 (MLP1 only, GELU out) ========
// Fix vs R12: phase q's ds_reads are issued at the END of phase q-1 (in flight across the
// barrier, hidden under other waves' MFMA) -- m196's isolated lever. 5 barriers/tile.
// Half-tile ledger (verified R12): prologue A0(0),B0(0),A1(0),B1(0),A0(1),B0(1);
// tile t: q0 stages A1(t+1), q1 B1(t+1), q2 A0(t+2), q3 B0(t+2); vmcnt(6) at q0.
// Wave (wm,wn of 2x4): C rows {mh*128 + wm*64 + 0..63}, cols {nh*128 + wn*32 + 0..31};
// phase q computes quadrant (mh=q>>1, nh=q&1) -> A-half mh freed after its 2 phases.
__global__ __launch_bounds__(512)
void gemm10_k(const u16* __restrict__ Ai, const u16* __restrict__ At, int lda,
              const u16* __restrict__ Bi, const u16* __restrict__ Bt, int ldb,
              const float* __restrict__ bias_i, const float* __restrict__ bias_t,
              u16* __restrict__ Ci, u16* __restrict__ Ct, int ldc, int K)
{
  constexpr int BK = 64;
  __shared__ u16 Ah[2][2][128 * BK];   // [buf][half] 64 KB
  __shared__ u16 Bh[2][2][128 * BK];   // 64 KB

  const int tid  = threadIdx.x;
  const int lane = tid & 63;
  const int wave = tid >> 6;
  const int wm = wave >> 2;            // 0..1
  const int wn = wave & 3;             // 0..3

  // XCD swizzle (nwg=288: %8==0, nwg/8=36 %gx(9)==0 -> panel-aligned chunks)
  const int gx = gridDim.x;
  const int nwg = gx * gridDim.y;
  const int n = blockIdx.x + gx * blockIdx.y;
  const int s_id = (n & 7) * (nwg >> 3) + (n >> 3);
  const int bx = s_id % gx;            // 0..8 ; 8 = txt
  const int by = s_id / gx;

  const bool ist = (bx == 8);
  const u16* Ab = ist ? At : (Ai + (long long)bx * 256 * lda);
  const u16* Bb = (ist ? Bt : Bi) + (long long)by * 256 * ldb;
  const float* bias = ist ? bias_t : bias_i;
  u16* C = ist ? Ct : Ci;

  // staging: half = 128 rows; per thread 2 gld16 (i=0,1 covering 64 rows each);
  // linear LDS dest, src octet ^ (row&7) (involution; row&7 == (lane>>3)&7 here)
  const int srow = wave * 8 + (lane >> 3);
  const int sgo  = ((lane & 7) ^ ((lane >> 3) & 7)) * 8;
  auto stageA = [&](int h, int b, int kk){
    #pragma unroll
    for (int i = 0; i < 2; ++i)
      gld16(Ab + (long long)(h * 128 + i * 64 + srow) * lda + kk + sgo,
            &Ah[b][h][(i * 64 + wave * 8) * BK]);
  };
  auto stageB = [&](int h, int b, int kk){
    #pragma unroll
    for (int i = 0; i < 2; ++i)
      gld16(Bb + (long long)(h * 128 + i * 64 + srow) * ldb + kk + sgo,
            &Bh[b][h][(i * 64 + wave * 8) * BK]);
  };

  const int frow = lane & 15;
  const int fx   = lane & 7;
  const int j0   = lane >> 4;

  f32x4 acc[2][4][2][2] = {};
  bf16x8 afA[2][4], bfA[2][2];         // set A (phases q0, q2)
  bf16x8 afB[2][4], bfB[2][2];         // set B (phases q1, q3)

  // quadrant fragment read: A-half mh rows wm*64+i*16+frow; B-half nh rows wn*32+k2*16+frow
  #define READQ(mh, nh, b, AF, BF)                                                     \
    _Pragma("unroll")                                                                  \
    for (int s = 0; s < 2; ++s){                                                       \
      const int oct = ((s * 4 + j0) ^ fx) * 8;                                         \
      _Pragma("unroll")                                                                \
      for (int i = 0; i < 4; ++i)                                                      \
        AF[s][i] = *(const bf16x8*)&Ah[b][mh][(wm * 64 + i * 16 + frow) * BK + oct];   \
      _Pragma("unroll")                                                                \
      for (int k2 = 0; k2 < 2; ++k2)                                                   \
        BF[s][k2] = *(const bf16x8*)&Bh[b][nh][(wn * 32 + k2 * 16 + frow) * BK + oct]; \
    }

  #define MFMAQ(mh, nh, AF, BF)                                                        \
    __builtin_amdgcn_s_setprio(1);                                                     \
    _Pragma("unroll")                                                                  \
    for (int s = 0; s < 2; ++s)                                                        \
      _Pragma("unroll")                                                                \
      for (int i = 0; i < 4; ++i)                                                      \
        _Pragma("unroll")                                                              \
        for (int k2 = 0; k2 < 2; ++k2)                                                 \
          acc[mh][i][nh][k2] = __builtin_amdgcn_mfma_f32_16x16x32_bf16(                \
              AF[s][i], BF[s][k2], acc[mh][i][nh][k2], 0, 0, 0);                       \
    __builtin_amdgcn_s_setprio(0);

  const int nt = K / BK;               // 32
  // prologue: 6 half-tiles (12 gld16/thread)
  stageA(0, 0, 0); stageB(0, 0, 0); stageA(1, 0, 0); stageB(1, 0, 0);
  stageA(0, 1, BK); stageB(0, 1, BK);
  __builtin_amdgcn_sched_barrier(0);

  for (int t = 0; t < nt; ++t){
    const int b = t & 1, nb = b ^ 1;
    // ---- q0 ----
    if (t + 1 < nt) stageA(1, nb, (t + 1) * BK);
    __builtin_amdgcn_sched_barrier(0);
    if (t == nt - 1) asm volatile("s_waitcnt vmcnt(0)" ::: "memory");
    else             asm volatile("s_waitcnt vmcnt(6)" ::: "memory");
    __builtin_amdgcn_sched_barrier(0);
    __builtin_amdgcn_s_barrier();                 // tile t resident
    __builtin_amdgcn_sched_barrier(0);
    READQ(0, 0, b, afA, bfA);
    MFMAQ(0, 0, afA, bfA);
    READQ(0, 1, b, afB, bfB);                     // prefetch q1 (in flight across barrier)
    __builtin_amdgcn_sched_barrier(0);
    __builtin_amdgcn_s_barrier();
    __builtin_amdgcn_sched_barrier(0);
    // ---- q1 ----
    if (t + 1 < nt) stageB(1, nb, (t + 1) * BK);
    __builtin_amdgcn_sched_barrier(0);
    MFMAQ(0, 1, afB, bfB);
    READQ(1, 0, b, afA, bfA);                     // prefetch q2
    __builtin_amdgcn_sched_barrier(0);
    __builtin_amdgcn_s_barrier();                 // frees A-half 0 (all waves past q1)
    __builtin_amdgcn_sched_barrier(0);
    // ---- q2 ----
    if (t + 2 < nt) stageA(0, b, (t + 2) * BK);   // overwrites Ah[b][0] (freed)
    __builtin_amdgcn_sched_barrier(0);
    MFMAQ(1, 0, afA, bfA);
    READQ(1, 1, b, afB, bfB);                     // prefetch q3
    __builtin_amdgcn_sched_barrier(0);
    __builtin_amdgcn_s_barrier();                 // frees B-half 0
    __builtin_amdgcn_sched_barrier(0);
    // ---- q3 ----
    if (t + 2 < nt) stageB(0, b, (t + 2) * BK);   // overwrites Bh[b][0] (freed)
    __builtin_amdgcn_sched_barrier(0);
    MFMAQ(1, 1, afB, bfB);
    __builtin_amdgcn_sched_barrier(0);
    __builtin_amdgcn_s_barrier();                 // frees A-half 1 / B-half 1
    __builtin_amdgcn_sched_barrier(0);
  }
  #undef READQ
  #undef MFMAQ

  // epilogue: bf16 gelu(acc+bias)
  const long long rowbase = ist ? 0 : (long long)bx * 256;
  #pragma unroll
  for (int mh = 0; mh < 2; ++mh)
    #pragma unroll
    for (int i = 0; i < 4; ++i)
      #pragma unroll
      for (int nh = 0; nh < 2; ++nh)
        #pragma unroll
        for (int k2 = 0; k2 < 2; ++k2){
          long long col = (long long)by * 256 + nh * 128 + wn * 32 + k2 * 16 + frow;
          float bv = bias[col];
          #pragma unroll
          for (int jj = 0; jj < 4; ++jj){
            long long row = rowbase + mh * 128 + wm * 64 + i * 16 + j0 * 4 + jj;
            float v = acc[mh][i][nh][k2][jj] + bv;
            float z2 = 1.5957691216057308f * (v + 0.044715f * v * v * v);
            C[row * (long long)ldc + col] = f2bf(v / (1.0f + __expf(-z2)));
          }
        }
}

// ======== 8-wave depth-2 GEMM, 128x128, BK=64 (QKV/proj/MLP2) ========
// MODE 0: f32 = acc+bias ; 2: f32 = res + gate[col]*(acc+bias)
// MODE 4 (QKV): fused RMSNorm+RoPE+scatter epilogue (verified R17/R18).
template<int MODE>
__global__ __launch_bounds__(512)
void gemm8_k(const u16* __restrict__ Ai, const u16* __restrict__ At, int lda,
             const u16* __restrict__ Bi, const u16* __restrict__ Bt, int ldb,
             const float* __restrict__ bias_i, const float* __restrict__ bias_t,
             const float* __restrict__ res_i,  const float* __restrict__ res_t,
             const float* __restrict__ gate_i, const float* __restrict__ gate_t,
             void* __restrict__ Ci, void* __restrict__ Ct, int ldc, int K,
             const float* __restrict__ qs_i, const float* __restrict__ ks_i,
             const float* __restrict__ qs_t, const float* __restrict__ ks_t,
             const float* __restrict__ pe,
             u16* __restrict__ Qo, u16* __restrict__ Ko, u16* __restrict__ Vo)
{
  constexpr int BK = 64;
  constexpr int MR = 4, NR = 2;
  constexpr int AI = 2, BI = 2;

  __shared__ u16 As[2][128 * BK];
  __shared__ u16 Bs[2][128 * BK];

  const int tid  = threadIdx.x;
  const int lane = tid & 63;
  const int wave = tid >> 6;
  const int wm = wave >> 2;
  const int wn = wave & 3;

  const int gx = gridDim.x;
  const int nwg = gx * gridDim.y;
  const int n = blockIdx.x + gx * blockIdx.y;
  const int s_id = (n & 7) * (nwg >> 3) + (n >> 3);
  const int bx = s_id % gx;
  const int by = s_id / gx;

  const bool ist = bx >= 16;
  const int rb = ist ? bx - 16 : bx;
  const u16* Ab = (ist ? At : Ai) + (long long)rb * 128 * lda;
  const u16* Bb = (ist ? Bt : Bi) + (long long)by * 128 * ldb;
  const float* bias = ist ? bias_t : bias_i;
  const float* res  = ist ? res_t  : res_i;
  const float* gate = ist ? gate_t : gate_i;
  void* C = ist ? Ct : Ci;

  const int srow = wave * 8 + (lane >> 3);
  const int sgo  = ((lane & 7) ^ ((lane >> 3) & 7)) * 8;
  const u16* agp[AI]; const u16* bgp[BI];
  int alo[AI], blo[BI];
  #pragma unroll
  for (int i = 0; i < AI; ++i){
    agp[i] = Ab + (long long)(i * 64 + srow) * lda + sgo;
    alo[i] = (i * 64 + wave * 8) * BK;
  }
  #pragma unroll
  for (int i = 0; i < BI; ++i){
    bgp[i] = Bb + (long long)(i * 64 + srow) * ldb + sgo;
    blo[i] = (i * 64 + wave * 8) * BK;
  }

  const int arow0 = wm * 64;
  const int frow  = lane & 15;
  const int fx    = lane & 7;
  const int j0    = lane >> 4;

  f32x4 acc[MR][NR] = {};

  #pragma unroll
  for (int i = 0; i < AI; ++i) gld16(agp[i], &As[0][alo[i]]);
  #pragma unroll
  for (int i = 0; i < BI; ++i) gld16(bgp[i], &Bs[0][blo[i]]);
  __builtin_amdgcn_sched_barrier(0);

  const int nt = K / BK;
  for (int t = 0; t < nt; ++t){
    if (t + 1 < nt){
      int k0 = (t + 1) * BK;
      int nb = (t + 1) & 1;
      #pragma unroll
      for (int i = 0; i < AI; ++i) gld16(agp[i] + k0, &As[nb][alo[i]]);
      #pragma unroll
      for (int i = 0; i < BI; ++i) gld16(bgp[i] + k0, &Bs[nb][blo[i]]);
      __builtin_amdgcn_sched_barrier(0);
      asm volatile("s_waitcnt vmcnt(4)" ::: "memory");
    } else {
      asm volatile("s_waitcnt vmcnt(0)" ::: "memory");
    }
    __builtin_amdgcn_sched_barrier(0);
    __builtin_amdgcn_s_barrier();
    __builtin_amdgcn_sched_barrier(0);

    const u16* as = As[t & 1];
    const u16* bs = Bs[t & 1];
    #pragma unroll
    for (int s = 0; s < 2; ++s){
      const int oct = (s * 4 + j0) ^ fx;
      bf16x8 bfr[NR];
      #pragma unroll
      for (int nn = 0; nn < NR; ++nn)
        bfr[nn] = *(const bf16x8*)&bs[(wn * 32 + nn * 16 + frow) * BK + oct * 8];
      __builtin_amdgcn_s_setprio(1);
      #pragma unroll
      for (int m = 0; m < MR; ++m){
        bf16x8 af = *(const bf16x8*)&as[(arow0 + m * 16 + frow) * BK + oct * 8];
        #pragma unroll
        for (int nn = 0; nn < NR; ++nn)
          acc[m][nn] = __builtin_amdgcn_mfma_f32_16x16x32_bf16(af, bfr[nn], acc[m][nn], 0, 0, 0);
      }
      __builtin_amdgcn_s_setprio(0);
    }
    __builtin_amdgcn_sched_barrier(0);
    __builtin_amdgcn_s_barrier();
    __builtin_amdgcn_sched_barrier(0);
  }

  const int lr = (lane >> 4) * 4;
  const int lc = lane & 15;

  if constexpr (MODE == 4){
    const int sstr = by >> 4;
    const int hh = by & 15;
    const int d0 = wn * 32;
    const long long posb = (ist ? 0 : 256) + (long long)rb * 128;
    float* red = (float*)&As[0][0];
    #pragma unroll
    for (int mi = 0; mi < MR; ++mi)
      #pragma unroll
      for (int ni = 0; ni < NR; ++ni){
        float bv = bias[by * 128 + d0 + ni * 16 + lc];
        #pragma unroll
        for (int j = 0; j < 4; ++j) acc[mi][ni][j] += bv;
      }
    if (sstr < 2){
      #pragma unroll
      for (int mi = 0; mi < MR; ++mi)
        #pragma unroll
        for (int j = 0; j < 4; ++j){
          float p = acc[mi][0][j] * acc[mi][0][j] + acc[mi][1][j] * acc[mi][1][j];
          #pragma unroll
          for (int o = 1; o < 16; o <<= 1) p += __shfl_xor(p, o, 64);
          if (lc == 0) red[(arow0 + mi * 16 + lr + j) * 4 + wn] = p;
        }
      __syncthreads();
      const float* scale = (sstr == 0) ? (ist ? qs_t : qs_i) : (ist ? ks_t : ks_i);
      const float fold = (sstr == 0) ? 0.08838834764831845f : 1.0f;
      u16* Out = (sstr == 0) ? Qo : Ko;
      #pragma unroll
      for (int mi = 0; mi < MR; ++mi)
        #pragma unroll
        for (int j = 0; j < 4; ++j){
          int rl = arow0 + mi * 16 + lr + j;
          float tot = red[rl * 4 + 0] + red[rl * 4 + 1] + red[rl * 4 + 2] + red[rl * 4 + 3];
          float rr = rsqrtf(tot * (1.0f / 128.0f) + 1e-6f) * fold;
          long long pos = posb + rl;
          u16* orow = Out + ((long long)hh * 2304 + pos) * 128;
          #pragma unroll
          for (int ni = 0; ni < NR; ++ni){
            int d = d0 + ni * 16 + lc;
            float xn = acc[mi][ni][j] * rr * scale[d];
            float pr = __shfl_xor(xn, 1, 64);
            int aa = d & 1;
            const float* pp = pe + pos * 256 + (d >> 1) * 4 + aa * 2;
            float e  = aa ? pr : xn;
            float o_ = aa ? xn : pr;
            orow[d] = f2bf(pp[0] * e + pp[1] * o_);
          }
        }
    } else {
      #pragma unroll
      for (int mi = 0; mi < MR; ++mi){
        long long pb = posb + arow0 + mi * 16 + lr;
        #pragma unroll
        for (int ni = 0; ni < NR; ++ni){
          int d = d0 + ni * 16 + lc;
          ushort4 o4;
          o4.x = f2bf(acc[mi][ni][0]); o4.y = f2bf(acc[mi][ni][1]);
          o4.z = f2bf(acc[mi][ni][2]); o4.w = f2bf(acc[mi][ni][3]);
          *(ushort4*)&Vo[((long long)hh * 128 + d) * 2304 + pb] = o4;
        }
      }
    }
    return;
  }

  const long long rowb = (long long)rb * 128 + arow0;
  const long long colb = (long long)by * 128 + wn * 32;
  #pragma unroll
  for (int mi = 0; mi < MR; ++mi){
    #pragma unroll
    for (int ni = 0; ni < NR; ++ni){
      long long col = colb + ni * 16 + lc;
      float bv = bias ? bias[col] : 0.0f;
      #pragma unroll
      for (int j = 0; j < 4; ++j){
        long long row = rowb + mi * 16 + lr + j;
        float v = acc[mi][ni][j] + bv;
        long long ci = row * (long long)ldc + col;
        if constexpr (MODE == 0) ((float*)C)[ci] = v;
        else if constexpr (MODE == 2) ((float*)C)[ci] = res[ci] + gate[col] * v;
      }
    }
  }
}

extern "C" void kernel_launch(void* const* d_in, const int* in_sizes, int n_in,
                              void* d_out, int out_size, void* d_ws, size_t ws_size,
                              hipStream_t stream)
{
  const float* img        = (const float*)d_in[0];
  const float* txt        = (const float*)d_in[1];
  const float* vec        = (const float*)d_in[2];
  const float* img_mod_w  = (const float*)d_in[3];
  const float* img_mod_b  = (const float*)d_in[4];
  const float* txt_mod_w  = (const float*)d_in[5];
  const float* txt_mod_b  = (const float*)d_in[6];
  const float* img_qkv_w  = (const float*)d_in[7];
  const float* img_qkv_b  = (const float*)d_in[8];
  const float* img_q_s    = (const float*)d_in[9];
  const float* img_k_s    = (const float*)d_in[10];
  const float* txt_qkv_w  = (const float*)d_in[11];
  const float* txt_qkv_b  = (const float*)d_in[12];
  const float* txt_q_s    = (const float*)d_in[13];
  const float* txt_k_s    = (const float*)d_in[14];
  const float* img_proj_w = (const float*)d_in[15];
  const float* img_proj_b = (const float*)d_in[16];
  const float* txt_proj_w = (const float*)d_in[17];
  const float* txt_proj_b = (const float*)d_in[18];
  const float* img_mlp_w1 = (const float*)d_in[19];
  const float* img_mlp_b1 = (const float*)d_in[20];
  const float* img_mlp_w2 = (const float*)d_in[21];
  const float* img_mlp_b2 = (const float*)d_in[22];
  const float* txt_mlp_w1 = (const float*)d_in[23];
  const float* txt_mlp_b1 = (const float*)d_in[24];
  const float* txt_mlp_w2 = (const float*)d_in[25];
  const float* txt_mlp_b2 = (const float*)d_in[26];
  const float* pe         = (const float*)d_in[27];

  char* ws = (char*)d_ws;
  size_t off = 0;
  auto alloc = [&](size_t b){ void* p = ws + off; off = (off + b + 255) & ~(size_t)255; return p; };

  u16* wq_i = (u16*)alloc(6144ll * 2048 * 2);
  u16* wq_t = (u16*)alloc(6144ll * 2048 * 2);
  u16* wp_i = (u16*)alloc(2048ll * 2048 * 2);
  u16* wp_t = (u16*)alloc(2048ll * 2048 * 2);
  u16* w1_i = (u16*)alloc(8192ll * 2048 * 2);
  u16* w1_t = (u16*)alloc(8192ll * 2048 * 2);
  u16* w2_i = (u16*)alloc(2048ll * 8192 * 2);
  u16* w2_t = (u16*)alloc(2048ll * 8192 * 2);
  float* mod_i = (float*)alloc(12288 * 4);
  float* mod_t = (float*)alloc(12288 * 4);
  float* mpart = (float*)alloc(4ll * 24576 * 4);
  u16* Qb   = (u16*)alloc(16ll * 2304 * 128 * 2);
  u16* Kb   = (u16*)alloc(16ll * 2304 * 128 * 2);
  u16* Vt   = (u16*)alloc(16ll * 2304 * 128 * 2);
  u16* attn = (u16*)alloc(2304ll * 2048 * 2);
  char* big = (char*)alloc(4ll * 2304 * 2304 * 4);

  u16*   xin_i = (u16*)big;
  u16*   xin_t = (u16*)(big + 8388608);
  float* y1_i  = (float*)big;
  float* y1_t  = (float*)(big + 16777216);
  u16*   ln2_i = (u16*)(big + 18874368);
  u16*   ln2_t = (u16*)(big + 27262976);
  u16*   h_i   = (u16*)(big + 28311552);
  u16*   h_t   = (u16*)(big + 61865984);

  // modulation vectors: K-split matvec + combine
  mod_mv_k<<<dim3(384, 4), 256, 0, stream>>>(vec, img_mod_w, txt_mod_w, mpart);
  mod_comb_k<<<96, 256, 0, stream>>>(mpart, img_mod_b, txt_mod_b, mod_i, mod_t);

  // merged weight cast + transpose
  {
    TcArgs a;
    const float* ins[8] = {img_qkv_w, txt_qkv_w, img_proj_w, txt_proj_w,
                           img_mlp_w1, txt_mlp_w1, img_mlp_w2, txt_mlp_w2};
    u16* outs[8] = {wq_i, wq_t, wp_i, wp_t, w1_i, w1_t, w2_i, w2_t};
    int Ks[8] = {2048, 2048, 2048, 2048, 2048, 2048, 8192, 8192};
    int Ns[8] = {6144, 6144, 2048, 2048, 8192, 8192, 2048, 2048};
    int b = 0;
    for (int i = 0; i < 8; ++i){
      a.in[i] = ins[i]; a.out[i] = outs[i]; a.K[i] = Ks[i]; a.N[i] = Ns[i];
      a.base[i] = b;
      b += (Ks[i] >> 6) * (Ns[i] >> 6);
    }
    a.base[8] = b;
    tcast64_k<<<b, 256, 0, stream>>>(a);
  }

  // LN1 + modulate
  ln_mod_k<<<2304, 256, 0, stream>>>(img, txt, mod_i, mod_i + 2048, mod_t, mod_t + 2048, xin_i, xin_t);

  // QKV GEMM with fused RMSNorm+RoPE+scatter epilogue
  gemm8_k<4><<<dim3(18, 48), 512, 0, stream>>>(xin_i, xin_t, 2048, wq_i, wq_t, 2048,
      img_qkv_b, txt_qkv_b, nullptr, nullptr, nullptr, nullptr, nullptr, nullptr, 0, 2048,
      img_q_s, img_k_s, txt_q_s, txt_k_s, pe, Qb, Kb, Vt);

  // fused flash attention
  fattn_k<<<dim3(18, 16), 512, 0, stream>>>(Qb, Kb, Vt, attn);

  // projections with residual + gate
  gemm8_k<2><<<dim3(18, 16), 512, 0, stream>>>(attn + 256 * 2048, attn, 2048, wp_i, wp_t, 2048,
      img_proj_b, txt_proj_b, img, txt, mod_i + 4096, mod_t + 4096, y1_i, y1_t, 2048, 2048,
      nullptr, nullptr, nullptr, nullptr, nullptr, nullptr, nullptr, nullptr);

  // LN2 + modulate
  ln_mod_k<<<2304, 256, 0, stream>>>(y1_i, y1_t, mod_i + 6144, mod_i + 8192, mod_t + 6144, mod_t + 8192, ln2_i, ln2_t);

  // MLP1: 8-phase interleaved gemm10 (256x256, 9x32 = 288 blocks)
  gemm10_k<<<dim3(9, 32), 512, 0, stream>>>(ln2_i, ln2_t, 2048, w1_i, w1_t, 2048,
      img_mlp_b1, txt_mlp_b1, h_i, h_t, 8192, 2048);

  // MLP2 with residual + gate -> final outputs
  float* out_img = (float*)d_out;
  float* out_txt = out_img + 2048ll * 2048;
  gemm8_k<2><<<dim3(18, 16), 512, 0, stream>>>(h_i, h_t, 8192, w2_i, w2_t, 8192,
      img_mlp_b2, txt_mlp_b2, y1_i, y1_t, mod_i + 10240, mod_t + 10240, out_img, out_txt, 2048, 8192,
      nullptr, nullptr, nullptr, nullptr, nullptr, nullptr, nullptr, nullptr);
}

// Round 21
// 777.343 us; speedup vs baseline: 1.0521x; 1.0521x over previous
//
#include <hip/hip_runtime.h>

using u16 = unsigned short;
typedef __bf16 bf16x8 __attribute__((ext_vector_type(8)));
typedef float f32x4 __attribute__((ext_vector_type(4)));

__device__ inline u16 f2bf(float f){
  unsigned u = __float_as_uint(f);
  u += 0x7fff + ((u >> 16) & 1);   // RNE
  return (u16)(u >> 16);
}
__device__ inline float bf2f(u16 u){ return __uint_as_float((unsigned)u << 16); }

__device__ inline float wredsum(float v){
  #pragma unroll
  for (int o = 32; o; o >>= 1) v += __shfl_xor(v, o, 64);
  return v;
}

// direct global -> LDS DMA, 16B per lane; lds base must be wave-uniform
__device__ inline void gld16(const u16* g, u16* lds){
  __builtin_amdgcn_global_load_lds(
      (const __attribute__((address_space(1))) unsigned int*)g,
      (__attribute__((address_space(3))) unsigned int*)lds, 16, 0, 0);
}

// ---------------- mod matvec, K-split x4 (R19) ----------------
__global__ void mod_mv_k(const float* __restrict__ vec,
    const float* __restrict__ wi, const float* __restrict__ wt,
    float* __restrict__ part)
{
  __shared__ float sv[512];
  __shared__ float red[4][64];
  int tid = threadIdx.x;
  int z = blockIdx.y;
  int k0 = z * 512;
  for (int i = tid; i < 512; i += 256){ float v = vec[k0 + i]; sv[i] = v / (1.0f + __expf(-v)); }
  __syncthreads();
  int j0 = blockIdx.x * 64;
  bool ist = j0 >= 12288;
  const float* w = ist ? wt : wi;
  int col = (ist ? j0 - 12288 : j0) + (tid & 63);
  int kq = tid >> 6;
  float acc = 0.f;
  const float* wp = w + (long long)k0 * 12288 + col;
  for (int k = kq * 128; k < kq * 128 + 128; ++k) acc += sv[k] * wp[(long long)k * 12288];
  red[kq][tid & 63] = acc;
  __syncthreads();
  if (kq == 0)
    part[(long long)z * 24576 + j0 + tid] = red[0][tid] + red[1][tid] + red[2][tid] + red[3][tid];
}

__global__ void mod_comb_k(const float* __restrict__ part,
    const float* __restrict__ bi, const float* __restrict__ bt,
    float* __restrict__ oi, float* __restrict__ ot)
{
  int idx = blockIdx.x * 256 + threadIdx.x;   // 0..24575
  float s = part[idx] + part[24576 + idx] + part[2 * 24576 + idx] + part[3 * 24576 + idx];
  if (idx >= 12288) ot[idx - 12288] = s + bt[idx - 12288];
  else              oi[idx] = s + bi[idx];
}

// ---------------- merged transpose + cast, 64x64 tiles ----------------
struct TcArgs {
  const float* in[8];
  u16* out[8];
  int K[8];
  int N[8];
  int base[9];
};

__global__ void tcast64_k(TcArgs a)
{
  __shared__ float tile[64][65];
  int bid = blockIdx.x;
  int w = 0;
  #pragma unroll
  for (int i = 0; i < 8; ++i) if (bid >= a.base[i + 1]) w = i + 1;
  const float* in = a.in[w];
  u16* out = a.out[w];
  int K = a.K[w], N = a.N[w];
  int local = bid - a.base[w];
  int tx = N >> 6;
  int n0 = (local % tx) * 64, k0 = (local / tx) * 64;
  int tid = threadIdx.x;
  int r = tid >> 2, c0 = (tid & 3) * 16;
  const float* ir = &in[(long long)(k0 + r) * N + n0 + c0];
  #pragma unroll
  for (int j = 0; j < 4; ++j){
    float4 v = *(const float4*)&ir[j * 4];
    tile[r][c0 + j * 4 + 0] = v.x; tile[r][c0 + j * 4 + 1] = v.y;
    tile[r][c0 + j * 4 + 2] = v.z; tile[r][c0 + j * 4 + 3] = v.w;
  }
  __syncthreads();
  int n = tid >> 2, ks = (tid & 3) * 16;
  u16* orow = &out[(long long)(n0 + n) * K + k0 + ks];
  #pragma unroll
  for (int j = 0; j < 4; ++j){
    ushort4 o;
    o.x = f2bf(tile[ks + j * 4 + 0][n]);
    o.y = f2bf(tile[ks + j * 4 + 1][n]);
    o.z = f2bf(tile[ks + j * 4 + 2][n]);
    o.w = f2bf(tile[ks + j * 4 + 3][n]);
    *(ushort4*)&orow[j * 4] = o;
  }
}

// ---------------- LayerNorm + modulate (img+txt merged) ----------------
__global__ void ln_mod_k(const float* __restrict__ xi, const float* __restrict__ xt,
    const float* __restrict__ sh_i, const float* __restrict__ sc_i,
    const float* __restrict__ sh_t, const float* __restrict__ sc_t,
    u16* __restrict__ oi, u16* __restrict__ ot)
{
  int row = blockIdx.x, tid = threadIdx.x;
  bool ist = row >= 2048;
  int r = ist ? row - 2048 : row;
  const float* xr = (ist ? xt : xi) + (long long)r * 2048;
  const float* sh = ist ? sh_t : sh_i;
  const float* sc = ist ? sc_t : sc_i;
  u16* orow = (ist ? ot : oi) + (long long)r * 2048;
  float v[8]; float s = 0.f, s2 = 0.f;
  #pragma unroll
  for (int j = 0; j < 8; ++j){ v[j] = xr[tid + j * 256]; s += v[j]; s2 += v[j] * v[j]; }
  s = wredsum(s); s2 = wredsum(s2);
  __shared__ float red[4][2];
  int wave = tid >> 6, lane = tid & 63;
  if (lane == 0){ red[wave][0] = s; red[wave][1] = s2; }
  __syncthreads();
  float S1 = red[0][0] + red[1][0] + red[2][0] + red[3][0];
  float S2 = red[0][1] + red[1][1] + red[2][1] + red[3][1];
  float mu = S1 * (1.0f / 2048.0f);
  float var = S2 * (1.0f / 2048.0f) - mu * mu;
  float rs = rsqrtf(var + 1e-6f);
  #pragma unroll
  for (int j = 0; j < 8; ++j){
    int c = tid + j * 256;
    orow[c] = f2bf((1.0f + sc[c]) * (v[j] - mu) * rs + sh[c]);
  }
}

// ======== fused flash attention, KV=64 tiles, 80KB LDS (R16) ========
__global__ __launch_bounds__(512)
void fattn_k(const u16* __restrict__ Qb, const u16* __restrict__ Kb,
             const u16* __restrict__ Vt, u16* __restrict__ attn)
{
  __shared__ u16 Kl[2][64 * 128];
  __shared__ u16 Vl[2][128 * 64];
  __shared__ u16 Pl[128 * 64];

  const int tid  = threadIdx.x;
  const int lane = tid & 63;
  const int wave = tid >> 6;
  const int h  = blockIdx.y;
  const int q0 = blockIdx.x * 128;

  const u16* Qg = Qb + ((long long)h * 2304 + q0) * 128;
  const u16* Kg = Kb + (long long)h * 2304 * 128;
  const u16* Vg = Vt + (long long)h * 128 * 2304;

  u16* Qlds = &Kl[0][0];

  const int r16 = wave * 4 + (lane >> 4);
  const int o16 = lane & 15;
  const int r8 = wave * 8 + (lane >> 3);
  const int o8 = lane & 7;

  #pragma unroll
  for (int i = 0; i < 4; ++i){
    int row = i * 32 + r16;
    gld16(Qg + (long long)row * 128 + ((o16 ^ (row & 7)) * 8),
          Qlds + (i * 32 + wave * 4) * 128);
  }
  __syncthreads();

  const int frow = lane & 15;
  const int j0   = lane >> 4;
  const int qrow = wave * 16 + frow;
  bf16x8 aq[4];
  #pragma unroll
  for (int s = 0; s < 4; ++s)
    aq[s] = *(const bf16x8*)&Qlds[qrow * 128 + (((s * 4 + j0) ^ (qrow & 7)) * 8)];
  __syncthreads();

  auto stageK = [&](int t, int b){
    #pragma unroll
    for (int i = 0; i < 2; ++i){
      int row = i * 32 + r16;
      gld16(Kg + (long long)(t * 64 + row) * 128 + ((o16 ^ (row & 7)) * 8),
            &Kl[b][(i * 32 + wave * 4) * 128]);
    }
  };
  auto stageV = [&](int t, int b){
    #pragma unroll
    for (int i = 0; i < 2; ++i){
      int row = i * 64 + r8;
      gld16(Vg + (long long)row * 2304 + t * 64 + ((o8 ^ (row & 7)) * 8),
            &Vl[b][(i * 64 + wave * 8) * 64]);
    }
  };

  stageK(0, 0); stageV(0, 0);
  __builtin_amdgcn_sched_barrier(0);

  float mrun[4], lrun[4];
  #pragma unroll
  for (int j = 0; j < 4; ++j){ mrun[j] = -3.0e38f; lrun[j] = 0.f; }
  f32x4 oacc[8] = {};

  for (int t = 0; t < 36; ++t){
    const int cur = t & 1;
    asm volatile("s_waitcnt vmcnt(0)" ::: "memory");
    __builtin_amdgcn_sched_barrier(0);
    __builtin_amdgcn_s_barrier();
    __builtin_amdgcn_sched_barrier(0);
    if (t + 1 < 36){ stageK(t + 1, cur ^ 1); stageV(t + 1, cur ^ 1); }
    __builtin_amdgcn_sched_barrier(0);

    f32x4 sacc[4] = {};
    #pragma unroll
    for (int s = 0; s < 4; ++s){
      #pragma unroll
      for (int n = 0; n < 4; ++n){
        int kr = n * 16 + frow;
        bf16x8 bk = *(const bf16x8*)&Kl[cur][kr * 128 + (((s * 4 + j0) ^ (kr & 7)) * 8)];
        sacc[n] = __builtin_amdgcn_mfma_f32_16x16x32_bf16(aq[s], bk, sacc[n], 0, 0, 0);
      }
    }

    float mnew[4], scl[4];
    #pragma unroll
    for (int j = 0; j < 4; ++j){
      float v = fmaxf(fmaxf(sacc[0][j], sacc[1][j]), fmaxf(sacc[2][j], sacc[3][j]));
      #pragma unroll
      for (int o = 8; o; o >>= 1) v = fmaxf(v, __shfl_xor(v, o, 64));
      mnew[j] = fmaxf(mrun[j], v);
      scl[j] = __expf(mrun[j] - mnew[j]);
      mrun[j] = mnew[j];
    }
    #pragma unroll
    for (int j = 0; j < 4; ++j){
      const int row = wave * 16 + j0 * 4 + j;
      float rsum = 0.f;
      #pragma unroll
      for (int n = 0; n < 4; ++n){
        float p = __expf(sacc[n][j] - mnew[j]);
        rsum += p;
        int col = n * 16 + frow;
        Pl[row * 64 + (((col >> 3) ^ (row & 7)) << 3) + (col & 7)] = f2bf(p);
      }
      #pragma unroll
      for (int o = 8; o; o >>= 1) rsum += __shfl_xor(rsum, o, 64);
      lrun[j] = lrun[j] * scl[j] + rsum;
      #pragma unroll
      for (int n = 0; n < 8; ++n) oacc[n][j] *= scl[j];
    }
    asm volatile("s_waitcnt lgkmcnt(0)" ::: "memory");
    __builtin_amdgcn_sched_barrier(0);

    #pragma unroll
    for (int s = 0; s < 2; ++s){
      bf16x8 ap = *(const bf16x8*)&Pl[qrow * 64 + (((s * 4 + j0) ^ (qrow & 7)) * 8)];
      #pragma unroll
      for (int n = 0; n < 8; ++n){
        int dr = n * 16 + frow;
        bf16x8 bv = *(const bf16x8*)&Vl[cur][dr * 64 + (((s * 4 + j0) ^ (dr & 7)) * 8)];
        oacc[n] = __builtin_amdgcn_mfma_f32_16x16x32_bf16(ap, bv, oacc[n], 0, 0, 0);
      }
    }
    __builtin_amdgcn_sched_barrier(0);
  }

  float inv[4];
  #pragma unroll
  for (int j = 0; j < 4; ++j) inv[j] = 1.0f / lrun[j];
  #pragma unroll
  for (int n = 0; n < 8; ++n){
    int d = n * 16 + frow;
    #pragma unroll
    for (int j = 0; j < 4; ++j){
      int row = wave * 16 + j0 * 4 + j;
      attn[(long long)(q0 + row) * 2048 + h * 128 + d] = f2bf(oacc[n][j] * inv[j]);
    }
  }
}

// ======== 8-wave depth-2 GEMM, 128x128, BK=64 (all GEMMs; R19-optimal) ========
// MODE 0: f32 = acc+bias ; 2: f32 = res + gate[col]*(acc+bias) ; 3: bf16 = gelu(acc+bias)
// MODE 4 (QKV): fused RMSNorm+RoPE+scatter epilogue (verified R17/R18).
template<int MODE>
__global__ __launch_bounds__(512)
void gemm8_k(const u16* __restrict__ Ai, const u16* __restrict__ At, int lda,
             const u16* __restrict__ Bi, const u16* __restrict__ Bt, int ldb,
             const float* __restrict__ bias_i, const float* __restrict__ bias_t,
             const float* __restrict__ res_i,  const float* __restrict__ res_t,
             const float* __restrict__ gate_i, const float* __restrict__ gate_t,
             void* __restrict__ Ci, void* __restrict__ Ct, int ldc, int K,
             const float* __restrict__ qs_i, const float* __restrict__ ks_i,
             const float* __restrict__ qs_t, const float* __restrict__ ks_t,
             const float* __restrict__ pe,
             u16* __restrict__ Qo, u16* __restrict__ Ko, u16* __restrict__ Vo)
{
  constexpr int BK = 64;
  constexpr int MR = 4, NR = 2;
  constexpr int AI = 2, BI = 2;

  __shared__ u16 As[2][128 * BK];
  __shared__ u16 Bs[2][128 * BK];

  const int tid  = threadIdx.x;
  const int lane = tid & 63;
  const int wave = tid >> 6;
  const int wm = wave >> 2;
  const int wn = wave & 3;

  const int gx = gridDim.x;
  const int nwg = gx * gridDim.y;
  const int n = blockIdx.x + gx * blockIdx.y;
  const int s_id = (n & 7) * (nwg >> 3) + (n >> 3);
  const int bx = s_id % gx;
  const int by = s_id / gx;

  const bool ist = bx >= 16;
  const int rb = ist ? bx - 16 : bx;
  const u16* Ab = (ist ? At : Ai) + (long long)rb * 128 * lda;
  const u16* Bb = (ist ? Bt : Bi) + (long long)by * 128 * ldb;
  const float* bias = ist ? bias_t : bias_i;
  const float* res  = ist ? res_t  : res_i;
  const float* gate = ist ? gate_t : gate_i;
  void* C = ist ? Ct : Ci;

  const int srow = wave * 8 + (lane >> 3);
  const int sgo  = ((lane & 7) ^ ((lane >> 3) & 7)) * 8;
  const u16* agp[AI]; const u16* bgp[BI];
  int alo[AI], blo[BI];
  #pragma unroll
  for (int i = 0; i < AI; ++i){
    agp[i] = Ab + (long long)(i * 64 + srow) * lda + sgo;
    alo[i] = (i * 64 + wave * 8) * BK;
  }
  #pragma unroll
  for (int i = 0; i < BI; ++i){
    bgp[i] = Bb + (long long)(i * 64 + srow) * ldb + sgo;
    blo[i] = (i * 64 + wave * 8) * BK;
  }

  const int arow0 = wm * 64;
  const int frow  = lane & 15;
  const int fx    = lane & 7;
  const int j0    = lane >> 4;

  f32x4 acc[MR][NR] = {};

  #pragma unroll
  for (int i = 0; i < AI; ++i) gld16(agp[i], &As[0][alo[i]]);
  #pragma unroll
  for (int i = 0; i < BI; ++i) gld16(bgp[i], &Bs[0][blo[i]]);
  __builtin_amdgcn_sched_barrier(0);

  const int nt = K / BK;
  for (int t = 0; t < nt; ++t){
    if (t + 1 < nt){
      int k0 = (t + 1) * BK;
      int nb = (t + 1) & 1;
      #pragma unroll
      for (int i = 0; i < AI; ++i) gld16(agp[i] + k0, &As[nb][alo[i]]);
      #pragma unroll
      for (int i = 0; i < BI; ++i) gld16(bgp[i] + k0, &Bs[nb][blo[i]]);
      __builtin_amdgcn_sched_barrier(0);
      asm volatile("s_waitcnt vmcnt(4)" ::: "memory");
    } else {
      asm volatile("s_waitcnt vmcnt(0)" ::: "memory");
    }
    __builtin_amdgcn_sched_barrier(0);
    __builtin_amdgcn_s_barrier();
    __builtin_amdgcn_sched_barrier(0);

    const u16* as = As[t & 1];
    const u16* bs = Bs[t & 1];
    #pragma unroll
    for (int s = 0; s < 2; ++s){
      const int oct = (s * 4 + j0) ^ fx;
      bf16x8 bfr[NR];
      #pragma unroll
      for (int nn = 0; nn < NR; ++nn)
        bfr[nn] = *(const bf16x8*)&bs[(wn * 32 + nn * 16 + frow) * BK + oct * 8];
      __builtin_amdgcn_s_setprio(1);
      #pragma unroll
      for (int m = 0; m < MR; ++m){
        bf16x8 af = *(const bf16x8*)&as[(arow0 + m * 16 + frow) * BK + oct * 8];
        #pragma unroll
        for (int nn = 0; nn < NR; ++nn)
          acc[m][nn] = __builtin_amdgcn_mfma_f32_16x16x32_bf16(af, bfr[nn], acc[m][nn], 0, 0, 0);
      }
      __builtin_amdgcn_s_setprio(0);
    }
    __builtin_amdgcn_sched_barrier(0);
    __builtin_amdgcn_s_barrier();
    __builtin_amdgcn_sched_barrier(0);
  }

  const int lr = (lane >> 4) * 4;
  const int lc = lane & 15;

  if constexpr (MODE == 4){
    const int sstr = by >> 4;
    const int hh = by & 15;
    const int d0 = wn * 32;
    const long long posb = (ist ? 0 : 256) + (long long)rb * 128;
    float* red = (float*)&As[0][0];
    #pragma unroll
    for (int mi = 0; mi < MR; ++mi)
      #pragma unroll
      for (int ni = 0; ni < NR; ++ni){
        float bv = bias[by * 128 + d0 + ni * 16 + lc];
        #pragma unroll
        for (int j = 0; j < 4; ++j) acc[mi][ni][j] += bv;
      }
    if (sstr < 2){
      #pragma unroll
      for (int mi = 0; mi < MR; ++mi)
        #pragma unroll
        for (int j = 0; j < 4; ++j){
          float p = acc[mi][0][j] * acc[mi][0][j] + acc[mi][1][j] * acc[mi][1][j];
          #pragma unroll
          for (int o = 1; o < 16; o <<= 1) p += __shfl_xor(p, o, 64);
          if (lc == 0) red[(arow0 + mi * 16 + lr + j) * 4 + wn] = p;
        }
      __syncthreads();
      const float* scale = (sstr == 0) ? (ist ? qs_t : qs_i) : (ist ? ks_t : ks_i);
      const float fold = (sstr == 0) ? 0.08838834764831845f : 1.0f;
      u16* Out = (sstr == 0) ? Qo : Ko;
      #pragma unroll
      for (int mi = 0; mi < MR; ++mi)
        #pragma unroll
        for (int j = 0; j < 4; ++j){
          int rl = arow0 + mi * 16 + lr + j;
          float tot = red[rl * 4 + 0] + red[rl * 4 + 1] + red[rl * 4 + 2] + red[rl * 4 + 3];
          float rr = rsqrtf(tot * (1.0f / 128.0f) + 1e-6f) * fold;
          long long pos = posb + rl;
          u16* orow = Out + ((long long)hh * 2304 + pos) * 128;
          #pragma unroll
          for (int ni = 0; ni < NR; ++ni){
            int d = d0 + ni * 16 + lc;
            float xn = acc[mi][ni][j] * rr * scale[d];
            float pr = __shfl_xor(xn, 1, 64);
            int aa = d & 1;
            const float* pp = pe + pos * 256 + (d >> 1) * 4 + aa * 2;
            float e  = aa ? pr : xn;
            float o_ = aa ? xn : pr;
            orow[d] = f2bf(pp[0] * e + pp[1] * o_);
          }
        }
    } else {
      #pragma unroll
      for (int mi = 0; mi < MR; ++mi){
        long long pb = posb + arow0 + mi * 16 + lr;
        #pragma unroll
        for (int ni = 0; ni < NR; ++ni){
          int d = d0 + ni * 16 + lc;
          ushort4 o4;
          o4.x = f2bf(acc[mi][ni][0]); o4.y = f2bf(acc[mi][ni][1]);
          o4.z = f2bf(acc[mi][ni][2]); o4.w = f2bf(acc[mi][ni][3]);
          *(ushort4*)&Vo[((long long)hh * 128 + d) * 2304 + pb] = o4;
        }
      }
    }
    return;
  }

  const long long rowb = (long long)rb * 128 + arow0;
  const long long colb = (long long)by * 128 + wn * 32;
  #pragma unroll
  for (int mi = 0; mi < MR; ++mi){
    #pragma unroll
    for (int ni = 0; ni < NR; ++ni){
      long long col = colb + ni * 16 + lc;
      float bv = bias ? bias[col] : 0.0f;
      #pragma unroll
      for (int j = 0; j < 4; ++j){
        long long row = rowb + mi * 16 + lr + j;
        float v = acc[mi][ni][j] + bv;
        long long ci = row * (long long)ldc + col;
        if constexpr (MODE == 0) ((float*)C)[ci] = v;
        else if constexpr (MODE == 2) ((float*)C)[ci] = res[ci] + gate[col] * v;
        else {
          float z2 = 1.5957691216057308f * (v + 0.044715f * v * v * v);
          ((u16*)C)[ci] = f2bf(v / (1.0f + __expf(-z2)));
        }
      }
    }
  }
}

extern "C" void kernel_launch(void* const* d_in, const int* in_sizes, int n_in,
                              void* d_out, int out_size, void* d_ws, size_t ws_size,
                              hipStream_t stream)
{
  const float* img        = (const float*)d_in[0];
  const float* txt        = (const float*)d_in[1];
  const float* vec        = (const float*)d_in[2];
  const float* img_mod_w  = (const float*)d_in[3];
  const float* img_mod_b  = (const float*)d_in[4];
  const float* txt_mod_w  = (const float*)d_in[5];
  const float* txt_mod_b  = (const float*)d_in[6];
  const float* img_qkv_w  = (const float*)d_in[7];
  const float* img_qkv_b  = (const float*)d_in[8];
  const float* img_q_s    = (const float*)d_in[9];
  const float* img_k_s    = (const float*)d_in[10];
  const float* txt_qkv_w  = (const float*)d_in[11];
  const float* txt_qkv_b  = (const float*)d_in[12];
  const float* txt_q_s    = (const float*)d_in[13];
  const float* txt_k_s    = (const float*)d_in[14];
  const float* img_proj_w = (const float*)d_in[15];
  const float* img_proj_b = (const float*)d_in[16];
  const float* txt_proj_w = (const float*)d_in[17];
  const float* txt_proj_b = (const float*)d_in[18];
  const float* img_mlp_w1 = (const float*)d_in[19];
  const float* img_mlp_b1 = (const float*)d_in[20];
  const float* img_mlp_w2 = (const float*)d_in[21];
  const float* img_mlp_b2 = (const float*)d_in[22];
  const float* txt_mlp_w1 = (const float*)d_in[23];
  const float* txt_mlp_b1 = (const float*)d_in[24];
  const float* txt_mlp_w2 = (const float*)d_in[25];
  const float* txt_mlp_b2 = (const float*)d_in[26];
  const float* pe         = (const float*)d_in[27];

  char* ws = (char*)d_ws;
  size_t off = 0;
  auto alloc = [&](size_t b){ void* p = ws + off; off = (off + b + 255) & ~(size_t)255; return p; };

  u16* wq_i = (u16*)alloc(6144ll * 2048 * 2);
  u16* wq_t = (u16*)alloc(6144ll * 2048 * 2);
  u16* wp_i = (u16*)alloc(2048ll * 2048 * 2);
  u16* wp_t = (u16*)alloc(2048ll * 2048 * 2);
  u16* w1_i = (u16*)alloc(8192ll * 2048 * 2);
  u16* w1_t = (u16*)alloc(8192ll * 2048 * 2);
  u16* w2_i = (u16*)alloc(2048ll * 8192 * 2);
  u16* w2_t = (u16*)alloc(2048ll * 8192 * 2);
  float* mod_i = (float*)alloc(12288 * 4);
  float* mod_t = (float*)alloc(12288 * 4);
  float* mpart = (float*)alloc(4ll * 24576 * 4);
  u16* Qb   = (u16*)alloc(16ll * 2304 * 128 * 2);
  u16* Kb   = (u16*)alloc(16ll * 2304 * 128 * 2);
  u16* Vt   = (u16*)alloc(16ll * 2304 * 128 * 2);
  u16* attn = (u16*)alloc(2304ll * 2048 * 2);
  char* big = (char*)alloc(4ll * 2304 * 2304 * 4);

  u16*   xin_i = (u16*)big;
  u16*   xin_t = (u16*)(big + 8388608);
  float* y1_i  = (float*)big;
  float* y1_t  = (float*)(big + 16777216);
  u16*   ln2_i = (u16*)(big + 18874368);
  u16*   ln2_t = (u16*)(big + 27262976);
  u16*   h_i   = (u16*)(big + 28311552);
  u16*   h_t   = (u16*)(big + 61865984);

  // modulation vectors: K-split matvec + combine
  mod_mv_k<<<dim3(384, 4), 256, 0, stream>>>(vec, img_mod_w, txt_mod_w, mpart);
  mod_comb_k<<<96, 256, 0, stream>>>(mpart, img_mod_b, txt_mod_b, mod_i, mod_t);

  // merged weight cast + transpose
  {
    TcArgs a;
    const float* ins[8] = {img_qkv_w, txt_qkv_w, img_proj_w, txt_proj_w,
                           img_mlp_w1, txt_mlp_w1, img_mlp_w2, txt_mlp_w2};
    u16* outs[8] = {wq_i, wq_t, wp_i, wp_t, w1_i, w1_t, w2_i, w2_t};
    int Ks[8] = {2048, 2048, 2048, 2048, 2048, 2048, 8192, 8192};
    int Ns[8] = {6144, 6144, 2048, 2048, 8192, 8192, 2048, 2048};
    int b = 0;
    for (int i = 0; i < 8; ++i){
      a.in[i] = ins[i]; a.out[i] = outs[i]; a.K[i] = Ks[i]; a.N[i] = Ns[i];
      a.base[i] = b;
      b += (Ks[i] >> 6) * (Ns[i] >> 6);
    }
    a.base[8] = b;
    tcast64_k<<<b, 256, 0, stream>>>(a);
  }

  // LN1 + modulate
  ln_mod_k<<<2304, 256, 0, stream>>>(img, txt, mod_i, mod_i + 2048, mod_t, mod_t + 2048, xin_i, xin_t);

  // QKV GEMM with fused RMSNorm+RoPE+scatter epilogue
  gemm8_k<4><<<dim3(18, 48), 512, 0, stream>>>(xin_i, xin_t, 2048, wq_i, wq_t, 2048,
      img_qkv_b, txt_qkv_b, nullptr, nullptr, nullptr, nullptr, nullptr, nullptr, 0, 2048,
      img_q_s, img_k_s, txt_q_s, txt_k_s, pe, Qb, Kb, Vt);

  // fused flash attention
  fattn_k<<<dim3(18, 16), 512, 0, stream>>>(Qb, Kb, Vt, attn);

  // projections with residual + gate
  gemm8_k<2><<<dim3(18, 16), 512, 0, stream>>>(attn + 256 * 2048, attn, 2048, wp_i, wp_t, 2048,
      img_proj_b, txt_proj_b, img, txt, mod_i + 4096, mod_t + 4096, y1_i, y1_t, 2048, 2048,
      nullptr, nullptr, nullptr, nullptr, nullptr, nullptr, nullptr, nullptr);

  // LN2 + modulate
  ln_mod_k<<<2304, 256, 0, stream>>>(y1_i, y1_t, mod_i + 6144, mod_i + 8192, mod_t + 6144, mod_t + 8192, ln2_i, ln2_t);

  // MLP1 (GELU fused; gemm8, 18x64 = 1152 blocks — R19-optimal)
  gemm8_k<3><<<dim3(18, 64), 512, 0, stream>>>(ln2_i, ln2_t, 2048, w1_i, w1_t, 2048,
      img_mlp_b1, txt_mlp_b1, nullptr, nullptr, nullptr, nullptr, h_i, h_t, 8192, 2048,
      nullptr, nullptr, nullptr, nullptr, nullptr, nullptr, nullptr, nullptr);

  // MLP2 with residual + gate -> final outputs
  float* out_img = (float*)d_out;
  float* out_txt = out_img + 2048ll * 2048;
  gemm8_k<2><<<dim3(18, 16), 512, 0, stream>>>(h_i, h_t, 8192, w2_i, w2_t, 8192,
      img_mlp_b2, txt_mlp_b2, y1_i, y1_t, mod_i + 10240, mod_t + 10240, out_img, out_txt, 2048, 8192,
      nullptr, nullptr, nullptr, nullptr, nullptr, nullptr, nullptr, nullptr);
}